// Round 10
// baseline (210.321 us; speedup 1.0000x reference)
//
#include <hip/hip_runtime.h>
#include <cstdint>
#include <cstddef>
#include <math.h>

// B=2, L=2048, E=1024, H=16, D=64
#define BB 2
#define LL 2048
#define EE 1024
#define HH 16
#define DD 64
#define MM (BB*LL)

typedef short short8 __attribute__((ext_vector_type(8)));
typedef float f32x4 __attribute__((ext_vector_type(4)));
typedef float f32x16 __attribute__((ext_vector_type(16)));

#define GPTR __attribute__((address_space(1)))
#define LPTR __attribute__((address_space(3)))

__device__ __forceinline__ unsigned short f32_bf16(float f) {
  union { float f; unsigned u; } c; c.f = f;
  c.u += 0x7fffu + ((c.u >> 16) & 1u);
  return (unsigned short)(c.u >> 16);
}

__device__ __forceinline__ unsigned pk_bf16(float lo, float hi) {
  unsigned r;
  asm("v_cvt_pk_bf16_f32 %0, %1, %2" : "=v"(r) : "v"(lo), "v"(hi));
  return r;
}
// v_permlane32_swap_b32 vdst, vsrc — operands must be DISTINCT live values.
__device__ __forceinline__ void swap32(unsigned &a, unsigned &b) {
  asm("v_permlane32_swap_b32 %0, %1" : "+v"(a), "+v"(b));
}
__device__ __forceinline__ float xh_max(float v) {
  union { float f; unsigned u; } a, b;
  a.f = v;
  asm("v_mov_b32 %0, %1" : "=&v"(b.u) : "v"(a.u));
  asm("v_permlane32_swap_b32 %0, %1" : "+v"(a.u), "+v"(b.u));
  return fmaxf(a.f, b.f);
}
__device__ __forceinline__ float xh_sum(float v) {
  union { float f; unsigned u; } a, b;
  a.f = v;
  asm("v_mov_b32 %0, %1" : "=&v"(b.u) : "v"(a.u));
  asm("v_permlane32_swap_b32 %0, %1" : "+v"(a.u), "+v"(b.u));
  return a.f + b.f;
}
__device__ __forceinline__ f32x16 zero16() {
  f32x16 v;
  #pragma unroll
  for (int e = 0; e < 16; ++e) v[e] = 0.f;
  return v;
}

// ---------------- fp32 -> bf16 conversion (x + 4 weights fused) ----------------
__global__ void cvt_all(const float* __restrict__ x,  const float* __restrict__ wq,
                        const float* __restrict__ wk, const float* __restrict__ wv,
                        const float* __restrict__ wo,
                        unsigned short* __restrict__ xb,  unsigned short* __restrict__ wqb,
                        unsigned short* __restrict__ wkb, unsigned short* __restrict__ wvb,
                        unsigned short* __restrict__ wob)
{
  int i = (blockIdx.x * 256 + threadIdx.x) * 4;
  if (i >= MM * EE + 4 * EE * EE) return;
  const float* s; unsigned short* d; int off;
  if (i < MM * EE) { s = x; d = xb; off = i; }
  else {
    int k = i - MM * EE;
    int w = k >> 20;               // EE*EE = 1<<20
    off = k & (EE * EE - 1);
    s = (w == 0) ? wq : (w == 1) ? wk : (w == 2) ? wv : wo;
    d = (w == 0) ? wqb : (w == 1) ? wkb : (w == 2) ? wvb : wob;
  }
  float4 v = *(const float4*)(s + off);
  union { unsigned short s[4]; uint2 u; } o;
  o.s[0] = f32_bf16(v.x); o.s[1] = f32_bf16(v.y);
  o.s[2] = f32_bf16(v.z); o.s[3] = f32_bf16(v.w);
  *(uint2*)(d + off) = o.u;
}

// ---------------- 128x128 bf16 GEMM (NT: A MxK, W NxK) ----------------
template<int MODE>
__global__ __launch_bounds__(256, 2)
void gemm128(const unsigned short* __restrict__ A,
             const unsigned short* __restrict__ W0,
             const unsigned short* __restrict__ W1,
             const unsigned short* __restrict__ W2,
             const float* __restrict__ mask,
             const float* __restrict__ bias,
             unsigned short* __restrict__ O0,
             unsigned short* __restrict__ O1,
             unsigned short* __restrict__ O2,
             float* __restrict__ OF)
{
  constexpr int K = EE;
  const int tid = threadIdx.x;
  const int lane = tid & 63;
  const int wid = tid >> 6;
  const int g = lane >> 4, li = lane & 15;
  const int m0 = blockIdx.y * 128;
  const int n0 = blockIdx.x * 128;
  const int z = blockIdx.z;

  const unsigned short* Wp = W0;
  if (MODE == 0) Wp = (z == 0) ? W0 : ((z == 1) ? W1 : W2);

  __shared__ unsigned short As[128 * 64];
  __shared__ unsigned short Bs[128 * 64];

  f32x4 acc[4][4];
  f32x4 zero = {0.f, 0.f, 0.f, 0.f};
  #pragma unroll
  for (int i = 0; i < 4; ++i)
    #pragma unroll
    for (int j = 0; j < 4; ++j) acc[i][j] = zero;

  const int wm = (wid >> 1) * 64;
  const int wn = (wid & 1) * 64;

  for (int kt = 0; kt < K; kt += 64) {
    #pragma unroll
    for (int j = 0; j < 4; ++j) {
      int c = j * 256 + tid;
      int row = c >> 3;
      int lcol = ((c & 7) * 16) ^ ((row & 7) << 4);
      __builtin_amdgcn_global_load_lds(
        (const GPTR void*)((const char*)(A + (size_t)(m0 + row) * K + kt) + lcol),
        (LPTR void*)((char*)As + c * 16), 16, 0, 0);
      __builtin_amdgcn_global_load_lds(
        (const GPTR void*)((const char*)(Wp + (size_t)(n0 + row) * K + kt) + lcol),
        (LPTR void*)((char*)Bs + c * 16), 16, 0, 0);
    }
    __syncthreads();

    #pragma unroll
    for (int kk = 0; kk < 2; ++kk) {
      short8 a[4], b[4];
      const int colb = (kk * 32 + g * 8) * 2;
      #pragma unroll
      for (int i = 0; i < 4; ++i) {
        int ar = wm + i * 16 + li;
        a[i] = *(const short8*)((const char*)As + ar * 128 + (colb ^ ((ar & 7) << 4)));
        int br = wn + i * 16 + li;
        b[i] = *(const short8*)((const char*)Bs + br * 128 + (colb ^ ((br & 7) << 4)));
      }
      #pragma unroll
      for (int i = 0; i < 4; ++i)
        #pragma unroll
        for (int j = 0; j < 4; ++j)
          acc[i][j] = __builtin_amdgcn_mfma_f32_16x16x32_bf16(a[i], b[j], acc[i][j], 0, 0, 0);
    }
    __syncthreads();
  }

  if (MODE == 0) {
    if (z == 2) {
      // V^T kv-blocked: per head [L/32][D=64][32], each 32-kv tile = 4KB contiguous
      #pragma unroll
      for (int i = 0; i < 4; ++i) {
        int mbase = m0 + wm + i * 16 + g * 4;
        int bb2 = mbase >> 11;
        int l0  = mbase & (LL - 1);
        float mk[4];
        #pragma unroll
        for (int r = 0; r < 4; ++r) mk[r] = mask[mbase + r];
        #pragma unroll
        for (int j = 0; j < 4; ++j) {
          int n = n0 + wn + j * 16 + li;
          int h2 = n >> 6, dd2 = n & 63;
          union { unsigned short s[4]; uint2 u; } o;
          #pragma unroll
          for (int r = 0; r < 4; ++r) o.s[r] = f32_bf16(acc[i][j][r] * mk[r]);
          size_t off = (size_t)(bb2 * HH + h2) * (LL * DD)
                     + (size_t)(l0 >> 5) * (DD * 32) + dd2 * 32 + (l0 & 31);
          *(uint2*)(O2 + off) = o.u;
        }
      }
    } else {
      unsigned short* Op = (z == 0) ? O0 : O1;
      const float sc = (z == 0) ? 0.125f * 1.44269504088896f : 1.0f;
      #pragma unroll
      for (int i = 0; i < 4; ++i) {
        #pragma unroll
        for (int r = 0; r < 4; ++r) {
          int m = m0 + wm + i * 16 + g * 4 + r;
          float mk = mask[m] * sc;
          int bb = m >> 11;
          int l  = m & (LL - 1);
          #pragma unroll
          for (int j = 0; j < 4; ++j) {
            int n = n0 + wn + j * 16 + li;
            int h = n >> 6, d = n & 63;
            size_t off = (((size_t)(bb * HH + h)) * LL + l) * DD + d;
            Op[off] = f32_bf16(acc[i][j][r] * mk);
          }
        }
      }
    }
  } else {
    #pragma unroll
    for (int i = 0; i < 4; ++i) {
      #pragma unroll
      for (int j = 0; j < 4; ++j) {
        int n = n0 + wn + j * 16 + li;
        float bv = bias[n];
        #pragma unroll
        for (int r = 0; r < 4; ++r) {
          int m = m0 + wm + i * 16 + g * 4 + r;
          OF[(size_t)m * EE + n] = acc[i][j][r] + bv;
        }
      }
    }
  }
}

// ---------------- causal flash attention: paired q-tiles, 4-wave kv-split ------
// Block p handles q-tiles qth=63-p AND qtl=p (65 tile-bodies, perfectly balanced).
// 4 waves: wave w takes kv tiles t ≡ w (mod 4), private state, 3-phase LDS merge.
// Grid 1024 x 256 thr -> 4 blocks/CU x 4 waves = 4 waves/SIMD (double R9's TLP).
__global__ __launch_bounds__(256, 4)
void attn6(const unsigned short* __restrict__ Q,
           const unsigned short* __restrict__ K,
           const unsigned short* __restrict__ VT,
           unsigned short* __restrict__ Y)
{
  const int tid = threadIdx.x, lane = tid & 63, w = tid >> 6;   // w: 0..3
  const int l31 = lane & 31, hi = lane >> 5;

  const int id = blockIdx.x;
  const int lo = id & 7;                    // XCD
  const int r_ = id >> 3;
  const int bh = (r_ & 3) * 8 + lo;         // 4 heads per XCD
  const int p  = r_ >> 2;                   // pair index 0..31
  const int qth = 63 - p;                   // heavy q-tile (32..63)
  const int qtl = p;                        // light q-tile (0..31)
  const int b = bh >> 4, h = bh & (HH - 1);
  const size_t kbase = (size_t)bh * LL * DD;

  const unsigned short* Kg  = K + kbase;
  const unsigned short* VTg = VT + kbase;   // kv-blocked [L/32][64][32]

  const int qrh = qth * 32 + l31;
  const int qrl = qtl * 32 + l31;

  short8 qfh[4], qfl[4];
  {
    const unsigned short* Qr = Q + kbase + (size_t)qrh * DD + hi * 8;
    #pragma unroll
    for (int kc = 0; kc < 4; ++kc) qfh[kc] = *(const short8*)(Qr + kc * 16);
    const unsigned short* Qs = Q + kbase + (size_t)qrl * DD + hi * 8;
    #pragma unroll
    for (int kc = 0; kc < 4; ++kc) qfl[kc] = *(const short8*)(Qs + kc * 16);
  }

  f32x16 oh0 = zero16(), oh1 = zero16(), ol0 = zero16(), ol1 = zero16();
  float mh = -INFINITY, lsh = 0.f, ml = -INFINITY, lsl = 0.f;

  short8 kA[4], vA[4], kB[4], vB[4];

  auto loadtile = [&](short8 (&kk)[4], short8 (&vv)[4], int t2) {
    const int kv0 = t2 << 5;
    const unsigned short* Kp = Kg + ((size_t)(kv0 + l31) << 6) + hi * 8;
    #pragma unroll
    for (int kc = 0; kc < 4; ++kc) kk[kc] = *(const short8*)(Kp + kc * 16);
    const unsigned short* Vp = VTg + (size_t)(kv0 >> 5) * (DD * 32) + l31 * 32 + hi * 8;
    vv[0] = *(const short8*)(Vp);
    vv[1] = *(const short8*)(Vp + 16);
    vv[2] = *(const short8*)(Vp + 32 * 32);
    vv[3] = *(const short8*)(Vp + 32 * 32 + 16);
  };

  loadtile(kA, vA, w);

  // S^T = K·Q^T into sref (by reference: no f32x16 copies)
  auto qk = [&](const short8 (&ck)[4], const short8 (&qf)[4], f32x16 &sref) {
    sref = zero16();
    __builtin_amdgcn_s_setprio(1);
    #pragma unroll
    for (int kc = 0; kc < 4; ++kc)
      sref = __builtin_amdgcn_mfma_f32_32x32x16_bf16(ck[kc], qf[kc], sref, 0, 0, 0);
    __builtin_amdgcn_s_setprio(0);
  };

  // online softmax + P fragments + PV (s mutated in place)
  auto process = [&](f32x16 &s, const short8 (&cv)[4],
                     float &mq, float &lq, f32x16 &o0, f32x16 &o1) {
    // max reduce as triples -> v_max3
    float r0 = fmaxf(fmaxf(fmaxf(s[0], s[8]),  fmaxf(s[1], s[9])),  fmaxf(s[2], s[10]));
    float r1 = fmaxf(fmaxf(fmaxf(s[3], s[11]), fmaxf(s[4], s[12])), fmaxf(s[5], s[13]));
    float r2 = fmaxf(fmaxf(s[6], s[14]), fmaxf(s[7], s[15]));
    float mv = xh_max(fmaxf(fmaxf(r0, r1), r2));

    if (!__all(mv <= mq + 8.0f)) {           // T13 defer-max (P bounded by 2^8)
      float mnew = fmaxf(mq, mv);
      float al = exp2f(mq - mnew);
      mq = mnew;
      lq *= al;
      #pragma unroll
      for (int e = 0; e < 16; ++e) { o0[e] *= al; o1[e] *= al; }
    }

    float ra[8];
    #pragma unroll
    for (int e = 0; e < 16; ++e) s[e] = exp2f(s[e] - mq);
    #pragma unroll
    for (int e = 0; e < 8; ++e) ra[e] = s[e] + s[e + 8];
    #pragma unroll
    for (int st = 4; st >= 1; st >>= 1)
      #pragma unroll
      for (int e = 0; e < 4; ++e) if (e < st) ra[e] += ra[e + st];
    lq += xh_sum(ra[0]);

    auto mkfrag = [&](int base) -> short8 {
      unsigned a0 = pk_bf16(s[base + 0], s[base + 1]);
      unsigned a1 = pk_bf16(s[base + 2], s[base + 3]);
      unsigned b0 = pk_bf16(s[base + 4], s[base + 5]);
      unsigned b1 = pk_bf16(s[base + 6], s[base + 7]);
      swap32(a0, b0);
      swap32(a1, b1);
      union { unsigned u[4]; short8 s8; } f;
      f.u[0] = a0; f.u[1] = a1; f.u[2] = b0; f.u[3] = b1;
      return f.s8;
    };
    short8 pf0 = mkfrag(0), pf1 = mkfrag(8);

    __builtin_amdgcn_s_setprio(1);
    o0 = __builtin_amdgcn_mfma_f32_32x32x16_bf16(cv[0], pf0, o0, 0, 0, 0);
    o0 = __builtin_amdgcn_mfma_f32_32x32x16_bf16(cv[1], pf1, o0, 0, 0, 0);
    o1 = __builtin_amdgcn_mfma_f32_32x32x16_bf16(cv[2], pf0, o1, 0, 0, 0);
    o1 = __builtin_amdgcn_mfma_f32_32x32x16_bf16(cv[3], pf1, o1, 0, 0, 0);
    __builtin_amdgcn_s_setprio(0);
  };

  auto body = [&](short8 (&ck)[4], short8 (&cv)[4],
                  short8 (&nk)[4], short8 (&nv)[4], int t) {
    if (t + 4 <= qth) loadtile(nk, nv, t + 4);

    f32x16 s;
    {  // heavy q-tile: always active
      qk(ck, qfh, s);
      if (t == qth) {
        #pragma unroll
        for (int i = 0; i < 16; ++i) {
          int kvr = (i & 3) + 8 * (i >> 2) + 4 * hi;
          if (kvr > l31) s[i] = -INFINITY;
        }
      }
      process(s, cv, mh, lsh, oh0, oh1);
    }
    if (t <= qtl) {  // light q-tile: shares this tile's K/V
      qk(ck, qfl, s);
      if (t == qtl) {
        #pragma unroll
        for (int i = 0; i < 16; ++i) {
          int kvr = (i & 3) + 8 * (i >> 2) + 4 * hi;
          if (kvr > l31) s[i] = -INFINITY;
        }
      }
      process(s, cv, ml, lsl, ol0, ol1);
    }
  };

  // wave w: tiles w, w+4, w+8, ... (register ping-pong, unroll 2)
  for (int t = w; t <= qth; t += 8) {
    body(kA, vA, kB, vB, t);
    if (t + 4 <= qth) body(kB, vB, kA, vA, t + 4);
  }

  // ---- 3-phase tree merge across 4 waves (LDS 34.8KB) ----
  // A: w1->mg[0], w3->mg[1]. B: w0 merges mg[0], w2 merges mg[1]. C: w2->mg[0],
  // w0 merges and writes. -inf-safe via fmaxf(x, -200) clamp (empty light states).
  __shared__ float mg[2][2][64][34];

  auto storeState = [&](int s_) {
    mg[s_][0][lane][0] = mh; mg[s_][0][lane][1] = lsh;
    mg[s_][1][lane][0] = ml; mg[s_][1][lane][1] = lsl;
    #pragma unroll
    for (int e = 0; e < 16; ++e) {
      mg[s_][0][lane][2 + e] = oh0[e]; mg[s_][0][lane][18 + e] = oh1[e];
      mg[s_][1][lane][2 + e] = ol0[e]; mg[s_][1][lane][18 + e] = ol1[e];
    }
  };
  auto mergeState = [&](int s_, int q, float &mq, float &lq, f32x16 &o0, f32x16 &o1) {
    float m1 = mg[s_][q][lane][0], l1 = mg[s_][q][lane][1];
    float M = fmaxf(mq, m1);
    float a0 = exp2f(fmaxf(mq - M, -200.0f));   // NaN/-inf safe
    float a1 = exp2f(fmaxf(m1 - M, -200.0f));
    lq = lq * a0 + l1 * a1;
    mq = M;
    #pragma unroll
    for (int e = 0; e < 16; ++e) {
      o0[e] = o0[e] * a0 + mg[s_][q][lane][2 + e]  * a1;
      o1[e] = o1[e] * a0 + mg[s_][q][lane][18 + e] * a1;
    }
  };

  if (w == 1) storeState(0);
  if (w == 3) storeState(1);
  __syncthreads();
  if (w == 0) { mergeState(0, 0, mh, lsh, oh0, oh1); mergeState(0, 1, ml, lsl, ol0, ol1); }
  if (w == 2) { mergeState(1, 0, mh, lsh, oh0, oh1); mergeState(1, 1, ml, lsl, ol0, ol1); }
  __syncthreads();
  if (w == 2) storeState(0);
  __syncthreads();
  if (w == 0) {
    mergeState(0, 0, mh, lsh, oh0, oh1);
    mergeState(0, 1, ml, lsl, ol0, ol1);
    #pragma unroll
    for (int q = 0; q < 2; ++q) {
      float lq = (q == 0) ? lsh : lsl;
      const f32x16& o0 = (q == 0) ? oh0 : ol0;
      const f32x16& o1 = (q == 0) ? oh1 : ol1;
      int qrow = (q == 0) ? qrh : qrl;
      float inv = 1.0f / lq;
      unsigned short* Yr = Y + ((size_t)b * LL + qrow) * EE + h * DD;
      #pragma unroll
      for (int rg = 0; rg < 4; ++rg) {
        union { unsigned short s[4]; uint2 u; } u0, u1;
        #pragma unroll
        for (int e = 0; e < 4; ++e) {
          int i = rg * 4 + e;
          u0.s[e] = f32_bf16(o0[i] * inv);
          u1.s[e] = f32_bf16(o1[i] * inv);
        }
        *(uint2*)(Yr + rg * 8 + hi * 4) = u0.u;
        *(uint2*)(Yr + 32 + rg * 8 + hi * 4) = u1.u;
      }
    }
  }
}

// ---------------- launch ----------------
extern "C" void kernel_launch(void* const* d_in, const int* in_sizes, int n_in,
                              void* d_out, int out_size, void* d_ws, size_t ws_size,
                              hipStream_t stream) {
  const float* x    = (const float*)d_in[0];
  const float* mask = (const float*)d_in[1];
  const float* Wq   = (const float*)d_in[2];
  const float* Wk   = (const float*)d_in[3];
  const float* Wv   = (const float*)d_in[4];
  const float* Wo   = (const float*)d_in[5];
  const float* bo   = (const float*)d_in[6];
  float* out = (float*)d_out;

  char* ws = (char*)d_ws;
  unsigned short* xb  = (unsigned short*)(ws);
  unsigned short* wqb = (unsigned short*)(ws + ((size_t)8  << 20));
  unsigned short* wkb = (unsigned short*)(ws + ((size_t)10 << 20));
  unsigned short* wvb = (unsigned short*)(ws + ((size_t)12 << 20));
  unsigned short* wob = (unsigned short*)(ws + ((size_t)14 << 20));
  unsigned short* Qb  = (unsigned short*)(ws + ((size_t)16 << 20));
  unsigned short* Kb  = (unsigned short*)(ws + ((size_t)24 << 20));
  unsigned short* VTb = (unsigned short*)(ws + ((size_t)32 << 20));
  unsigned short* Yb  = (unsigned short*)(ws + ((size_t)40 << 20));

  cvt_all<<<8192, 256, 0, stream>>>(x, Wq, Wk, Wv, Wo, xb, wqb, wkb, wvb, wob);

  gemm128<0><<<dim3(EE / 128, MM / 128, 3), 256, 0, stream>>>(
      xb, wqb, wkb, wvb, mask, nullptr, Qb, Kb, VTb, nullptr);

  attn6<<<dim3(1024), 256, 0, stream>>>(Qb, Kb, VTb, Yb);

  gemm128<1><<<dim3(EE / 128, MM / 128, 1), 256, 0, stream>>>(
      Yb, wob, nullptr, nullptr, nullptr, bo, nullptr, nullptr, nullptr, out);
}

// Round 11
// 120.676 us; speedup vs baseline: 1.7429x; 1.7429x over previous
//
#include <hip/hip_runtime.h>
#include <cstdint>
#include <cstddef>
#include <math.h>

// B=2, L=2048, E=1024, H=16, D=64
#define BB 2
#define LL 2048
#define EE 1024
#define HH 16
#define DD 64
#define MM (BB*LL)

typedef short short8 __attribute__((ext_vector_type(8)));
typedef float f32x4 __attribute__((ext_vector_type(4)));
typedef float f32x16 __attribute__((ext_vector_type(16)));

#define GPTR __attribute__((address_space(1)))
#define LPTR __attribute__((address_space(3)))

__device__ __forceinline__ unsigned short f32_bf16(float f) {
  union { float f; unsigned u; } c; c.f = f;
  c.u += 0x7fffu + ((c.u >> 16) & 1u);
  return (unsigned short)(c.u >> 16);
}

__device__ __forceinline__ unsigned pk_bf16(float lo, float hi) {
  unsigned r;
  asm("v_cvt_pk_bf16_f32 %0, %1, %2" : "=v"(r) : "v"(lo), "v"(hi));
  return r;
}
// v_permlane32_swap_b32 vdst, vsrc — operands must be DISTINCT live values.
__device__ __forceinline__ void swap32(unsigned &a, unsigned &b) {
  asm("v_permlane32_swap_b32 %0, %1" : "+v"(a), "+v"(b));
}
__device__ __forceinline__ float xh_max(float v) {
  union { float f; unsigned u; } a, b;
  a.f = v;
  asm("v_mov_b32 %0, %1" : "=&v"(b.u) : "v"(a.u));
  asm("v_permlane32_swap_b32 %0, %1" : "+v"(a.u), "+v"(b.u));
  return fmaxf(a.f, b.f);
}
__device__ __forceinline__ float xh_sum(float v) {
  union { float f; unsigned u; } a, b;
  a.f = v;
  asm("v_mov_b32 %0, %1" : "=&v"(b.u) : "v"(a.u));
  asm("v_permlane32_swap_b32 %0, %1" : "+v"(a.u), "+v"(b.u));
  return a.f + b.f;
}
__device__ __forceinline__ f32x16 zero16() {
  f32x16 v;
  #pragma unroll
  for (int e = 0; e < 16; ++e) v[e] = 0.f;
  return v;
}

// ---------------- fp32 -> bf16 conversion (x + 4 weights fused) ----------------
__global__ void cvt_all(const float* __restrict__ x,  const float* __restrict__ wq,
                        const float* __restrict__ wk, const float* __restrict__ wv,
                        const float* __restrict__ wo,
                        unsigned short* __restrict__ xb,  unsigned short* __restrict__ wqb,
                        unsigned short* __restrict__ wkb, unsigned short* __restrict__ wvb,
                        unsigned short* __restrict__ wob)
{
  int i = (blockIdx.x * 256 + threadIdx.x) * 4;
  if (i >= MM * EE + 4 * EE * EE) return;
  const float* s; unsigned short* d; int off;
  if (i < MM * EE) { s = x; d = xb; off = i; }
  else {
    int k = i - MM * EE;
    int w = k >> 20;               // EE*EE = 1<<20
    off = k & (EE * EE - 1);
    s = (w == 0) ? wq : (w == 1) ? wk : (w == 2) ? wv : wo;
    d = (w == 0) ? wqb : (w == 1) ? wkb : (w == 2) ? wvb : wob;
  }
  float4 v = *(const float4*)(s + off);
  union { unsigned short s[4]; uint2 u; } o;
  o.s[0] = f32_bf16(v.x); o.s[1] = f32_bf16(v.y);
  o.s[2] = f32_bf16(v.z); o.s[3] = f32_bf16(v.w);
  *(uint2*)(d + off) = o.u;
}

// ---------------- 128x128 bf16 GEMM (NT: A MxK, W NxK) ----------------
template<int MODE>
__global__ __launch_bounds__(256, 2)
void gemm128(const unsigned short* __restrict__ A,
             const unsigned short* __restrict__ W0,
             const unsigned short* __restrict__ W1,
             const unsigned short* __restrict__ W2,
             const float* __restrict__ mask,
             const float* __restrict__ bias,
             unsigned short* __restrict__ O0,
             unsigned short* __restrict__ O1,
             unsigned short* __restrict__ O2,
             float* __restrict__ OF)
{
  constexpr int K = EE;
  const int tid = threadIdx.x;
  const int lane = tid & 63;
  const int wid = tid >> 6;
  const int g = lane >> 4, li = lane & 15;
  const int m0 = blockIdx.y * 128;
  const int n0 = blockIdx.x * 128;
  const int z = blockIdx.z;

  const unsigned short* Wp = W0;
  if (MODE == 0) Wp = (z == 0) ? W0 : ((z == 1) ? W1 : W2);

  __shared__ unsigned short As[128 * 64];
  __shared__ unsigned short Bs[128 * 64];

  f32x4 acc[4][4];
  f32x4 zero = {0.f, 0.f, 0.f, 0.f};
  #pragma unroll
  for (int i = 0; i < 4; ++i)
    #pragma unroll
    for (int j = 0; j < 4; ++j) acc[i][j] = zero;

  const int wm = (wid >> 1) * 64;
  const int wn = (wid & 1) * 64;

  for (int kt = 0; kt < K; kt += 64) {
    #pragma unroll
    for (int j = 0; j < 4; ++j) {
      int c = j * 256 + tid;
      int row = c >> 3;
      int lcol = ((c & 7) * 16) ^ ((row & 7) << 4);
      __builtin_amdgcn_global_load_lds(
        (const GPTR void*)((const char*)(A + (size_t)(m0 + row) * K + kt) + lcol),
        (LPTR void*)((char*)As + c * 16), 16, 0, 0);
      __builtin_amdgcn_global_load_lds(
        (const GPTR void*)((const char*)(Wp + (size_t)(n0 + row) * K + kt) + lcol),
        (LPTR void*)((char*)Bs + c * 16), 16, 0, 0);
    }
    __syncthreads();

    #pragma unroll
    for (int kk = 0; kk < 2; ++kk) {
      short8 a[4], b[4];
      const int colb = (kk * 32 + g * 8) * 2;
      #pragma unroll
      for (int i = 0; i < 4; ++i) {
        int ar = wm + i * 16 + li;
        a[i] = *(const short8*)((const char*)As + ar * 128 + (colb ^ ((ar & 7) << 4)));
        int br = wn + i * 16 + li;
        b[i] = *(const short8*)((const char*)Bs + br * 128 + (colb ^ ((br & 7) << 4)));
      }
      #pragma unroll
      for (int i = 0; i < 4; ++i)
        #pragma unroll
        for (int j = 0; j < 4; ++j)
          acc[i][j] = __builtin_amdgcn_mfma_f32_16x16x32_bf16(a[i], b[j], acc[i][j], 0, 0, 0);
    }
    __syncthreads();
  }

  if (MODE == 0) {
    if (z == 2) {
      // V^T kv-blocked: per head [L/32][D=64][32], each 32-kv tile = 4KB contiguous
      #pragma unroll
      for (int i = 0; i < 4; ++i) {
        int mbase = m0 + wm + i * 16 + g * 4;
        int bb2 = mbase >> 11;
        int l0  = mbase & (LL - 1);
        float mk[4];
        #pragma unroll
        for (int r = 0; r < 4; ++r) mk[r] = mask[mbase + r];
        #pragma unroll
        for (int j = 0; j < 4; ++j) {
          int n = n0 + wn + j * 16 + li;
          int h2 = n >> 6, dd2 = n & 63;
          union { unsigned short s[4]; uint2 u; } o;
          #pragma unroll
          for (int r = 0; r < 4; ++r) o.s[r] = f32_bf16(acc[i][j][r] * mk[r]);
          size_t off = (size_t)(bb2 * HH + h2) * (LL * DD)
                     + (size_t)(l0 >> 5) * (DD * 32) + dd2 * 32 + (l0 & 31);
          *(uint2*)(O2 + off) = o.u;
        }
      }
    } else {
      unsigned short* Op = (z == 0) ? O0 : O1;
      const float sc = (z == 0) ? 0.125f * 1.44269504088896f : 1.0f;
      #pragma unroll
      for (int i = 0; i < 4; ++i) {
        #pragma unroll
        for (int r = 0; r < 4; ++r) {
          int m = m0 + wm + i * 16 + g * 4 + r;
          float mk = mask[m] * sc;
          int bb = m >> 11;
          int l  = m & (LL - 1);
          #pragma unroll
          for (int j = 0; j < 4; ++j) {
            int n = n0 + wn + j * 16 + li;
            int h = n >> 6, d = n & 63;
            size_t off = (((size_t)(bb * HH + h)) * LL + l) * DD + d;
            Op[off] = f32_bf16(acc[i][j][r] * mk);
          }
        }
      }
    }
  } else {
    #pragma unroll
    for (int i = 0; i < 4; ++i) {
      #pragma unroll
      for (int j = 0; j < 4; ++j) {
        int n = n0 + wn + j * 16 + li;
        float bv = bias[n];
        #pragma unroll
        for (int r = 0; r < 4; ++r) {
          int m = m0 + wm + i * 16 + g * 4 + r;
          OF[(size_t)m * EE + n] = acc[i][j][r] + bv;
        }
      }
    }
  }
}

// ---------------- causal flash attention: paired q-tiles, 4-wave kv-split, -----
// ---------------- TWO SEQUENTIAL PHASES to keep VGPR under the 4-wave cap ------
// Block p: phase H = q-tile 63-p, phase L = q-tile p; each phase: wave w takes
// kv tiles t ≡ w (mod 4), private (m,l,O), 3-phase LDS merge, wave0 writes Y.
// Only ONE q-state + ONE K/V reg buffer live at a time (~110 VGPR).
// Grid 1024 x 256 thr = 4 blocks/CU x 4 waves = 4 waves/SIMD.
__global__ __launch_bounds__(256, 4)
void attn7(const unsigned short* __restrict__ Q,
           const unsigned short* __restrict__ K,
           const unsigned short* __restrict__ VT,
           unsigned short* __restrict__ Y)
{
  const int tid = threadIdx.x, lane = tid & 63, w = tid >> 6;   // w: 0..3
  const int l31 = lane & 31, hi = lane >> 5;

  const int id = blockIdx.x;
  const int lo = id & 7;                    // XCD
  const int r_ = id >> 3;
  const int bh = (r_ & 3) * 8 + lo;         // 4 heads per XCD
  const int p  = r_ >> 2;                   // pair index 0..31
  const int b = bh >> 4, h = bh & (HH - 1);
  const size_t kbase = (size_t)bh * LL * DD;

  const unsigned short* Kg  = K + kbase;
  const unsigned short* VTg = VT + kbase;   // kv-blocked [L/32][64][32]

  __shared__ float mg[2][64][34];           // 17.4 KB merge scratch

  auto run_phase = [&](int qt) {
    const int qrow = qt * 32 + l31;

    short8 qf[4];
    {
      const unsigned short* Qr = Q + kbase + (size_t)qrow * DD + hi * 8;
      #pragma unroll
      for (int kc = 0; kc < 4; ++kc) qf[kc] = *(const short8*)(Qr + kc * 16);
    }

    f32x16 o0 = zero16(), o1 = zero16();
    float mq = -INFINITY, lq = 0.f;

    short8 kA[4], vA[4];

    for (int t = w; t <= qt; t += 4) {
      // load tile t (K tile contiguous 4KB, V^T tile = one 4KB block)
      {
        const int kv0 = t << 5;
        const unsigned short* Kp = Kg + ((size_t)(kv0 + l31) << 6) + hi * 8;
        #pragma unroll
        for (int kc = 0; kc < 4; ++kc) kA[kc] = *(const short8*)(Kp + kc * 16);
        const unsigned short* Vp = VTg + (size_t)(kv0 >> 5) * (DD * 32) + l31 * 32 + hi * 8;
        vA[0] = *(const short8*)(Vp);
        vA[1] = *(const short8*)(Vp + 16);
        vA[2] = *(const short8*)(Vp + 32 * 32);
        vA[3] = *(const short8*)(Vp + 32 * 32 + 16);
      }

      // S^T = K·Q^T (log2 units)
      f32x16 s = zero16();
      __builtin_amdgcn_s_setprio(1);
      #pragma unroll
      for (int kc = 0; kc < 4; ++kc)
        s = __builtin_amdgcn_mfma_f32_32x32x16_bf16(kA[kc], qf[kc], s, 0, 0, 0);
      __builtin_amdgcn_s_setprio(0);

      // causal mask on the diagonal tile
      if (t == qt) {
        #pragma unroll
        for (int i = 0; i < 16; ++i) {
          int kvr = (i & 3) + 8 * (i >> 2) + 4 * hi;
          if (kvr > l31) s[i] = -INFINITY;
        }
      }

      // online softmax (exp2 domain)
      float r0 = fmaxf(fmaxf(fmaxf(s[0], s[8]),  fmaxf(s[1], s[9])),  fmaxf(s[2], s[10]));
      float r1 = fmaxf(fmaxf(fmaxf(s[3], s[11]), fmaxf(s[4], s[12])), fmaxf(s[5], s[13]));
      float r2 = fmaxf(fmaxf(s[6], s[14]), fmaxf(s[7], s[15]));
      float mv = xh_max(fmaxf(fmaxf(r0, r1), r2));

      if (!__all(mv <= mq + 8.0f)) {           // T13 defer-max
        float mnew = fmaxf(mq, mv);
        float al = exp2f(mq - mnew);
        mq = mnew;
        lq *= al;
        #pragma unroll
        for (int e = 0; e < 16; ++e) { o0[e] *= al; o1[e] *= al; }
      }

      float ra[8];
      #pragma unroll
      for (int e = 0; e < 16; ++e) s[e] = exp2f(s[e] - mq);
      #pragma unroll
      for (int e = 0; e < 8; ++e) ra[e] = s[e] + s[e + 8];
      #pragma unroll
      for (int st = 4; st >= 1; st >>= 1)
        #pragma unroll
        for (int e = 0; e < 4; ++e) if (e < st) ra[e] += ra[e + st];
      lq += xh_sum(ra[0]);

      // P fragments: cvt_pk + permlane32_swap (T12)
      auto mkfrag = [&](int base) -> short8 {
        unsigned a0 = pk_bf16(s[base + 0], s[base + 1]);
        unsigned a1 = pk_bf16(s[base + 2], s[base + 3]);
        unsigned b0 = pk_bf16(s[base + 4], s[base + 5]);
        unsigned b1 = pk_bf16(s[base + 6], s[base + 7]);
        swap32(a0, b0);
        swap32(a1, b1);
        union { unsigned u[4]; short8 s8; } f;
        f.u[0] = a0; f.u[1] = a1; f.u[2] = b0; f.u[3] = b1;
        return f.s8;
      };
      short8 pf0 = mkfrag(0), pf1 = mkfrag(8);

      // O^T += V^T · P^T
      __builtin_amdgcn_s_setprio(1);
      o0 = __builtin_amdgcn_mfma_f32_32x32x16_bf16(vA[0], pf0, o0, 0, 0, 0);
      o0 = __builtin_amdgcn_mfma_f32_32x32x16_bf16(vA[1], pf1, o0, 0, 0, 0);
      o1 = __builtin_amdgcn_mfma_f32_32x32x16_bf16(vA[2], pf0, o1, 0, 0, 0);
      o1 = __builtin_amdgcn_mfma_f32_32x32x16_bf16(vA[3], pf1, o1, 0, 0, 0);
      __builtin_amdgcn_s_setprio(0);
    }

    // ---- 3-phase tree merge across 4 waves ----
    auto storeState = [&](int s_) {
      mg[s_][lane][0] = mq; mg[s_][lane][1] = lq;
      #pragma unroll
      for (int e = 0; e < 16; ++e) {
        mg[s_][lane][2 + e]  = o0[e];
        mg[s_][lane][18 + e] = o1[e];
      }
    };
    auto mergeState = [&](int s_) {
      float m1 = mg[s_][lane][0], l1 = mg[s_][lane][1];
      float M = fmaxf(mq, m1);
      float a0 = exp2f(fmaxf(mq - M, -200.0f));   // -inf safe (empty waves)
      float a1 = exp2f(fmaxf(m1 - M, -200.0f));
      lq = lq * a0 + l1 * a1;
      mq = M;
      #pragma unroll
      for (int e = 0; e < 16; ++e) {
        o0[e] = o0[e] * a0 + mg[s_][lane][2 + e]  * a1;
        o1[e] = o1[e] * a0 + mg[s_][lane][18 + e] * a1;
      }
    };

    __syncthreads();                 // protect mg reuse across phases
    if (w == 1) storeState(0);
    if (w == 3) storeState(1);
    __syncthreads();
    if (w == 0) mergeState(0);
    if (w == 2) mergeState(1);
    __syncthreads();
    if (w == 2) storeState(0);
    __syncthreads();
    if (w == 0) {
      mergeState(0);
      float inv = 1.0f / lq;
      unsigned short* Yr = Y + ((size_t)b * LL + qrow) * EE + h * DD;
      #pragma unroll
      for (int rg = 0; rg < 4; ++rg) {
        union { unsigned short s[4]; uint2 u; } u0, u1;
        #pragma unroll
        for (int e = 0; e < 4; ++e) {
          int i = rg * 4 + e;
          u0.s[e] = f32_bf16(o0[i] * inv);
          u1.s[e] = f32_bf16(o1[i] * inv);
        }
        *(uint2*)(Yr + rg * 8 + hi * 4) = u0.u;
        *(uint2*)(Yr + 32 + rg * 8 + hi * 4) = u1.u;
      }
    }
  };

  run_phase(63 - p);   // heavy q-tile
  run_phase(p);        // light q-tile
}

// ---------------- launch ----------------
extern "C" void kernel_launch(void* const* d_in, const int* in_sizes, int n_in,
                              void* d_out, int out_size, void* d_ws, size_t ws_size,
                              hipStream_t stream) {
  const float* x    = (const float*)d_in[0];
  const float* mask = (const float*)d_in[1];
  const float* Wq   = (const float*)d_in[2];
  const float* Wk   = (const float*)d_in[3];
  const float* Wv   = (const float*)d_in[4];
  const float* Wo   = (const float*)d_in[5];
  const float* bo   = (const float*)d_in[6];
  float* out = (float*)d_out;

  char* ws = (char*)d_ws;
  unsigned short* xb  = (unsigned short*)(ws);
  unsigned short* wqb = (unsigned short*)(ws + ((size_t)8  << 20));
  unsigned short* wkb = (unsigned short*)(ws + ((size_t)10 << 20));
  unsigned short* wvb = (unsigned short*)(ws + ((size_t)12 << 20));
  unsigned short* wob = (unsigned short*)(ws + ((size_t)14 << 20));
  unsigned short* Qb  = (unsigned short*)(ws + ((size_t)16 << 20));
  unsigned short* Kb  = (unsigned short*)(ws + ((size_t)24 << 20));
  unsigned short* VTb = (unsigned short*)(ws + ((size_t)32 << 20));
  unsigned short* Yb  = (unsigned short*)(ws + ((size_t)40 << 20));

  cvt_all<<<8192, 256, 0, stream>>>(x, Wq, Wk, Wv, Wo, xb, wqb, wkb, wvb, wob);

  gemm128<0><<<dim3(EE / 128, MM / 128, 3), 256, 0, stream>>>(
      xb, wqb, wkb, wvb, mask, nullptr, Qb, Kb, VTb, nullptr);

  attn7<<<dim3(1024), 256, 0, stream>>>(Qb, Kb, VTb, Yb);

  gemm128<1><<<dim3(EE / 128, MM / 128, 1), 256, 0, stream>>>(
      Yb, wob, nullptr, nullptr, nullptr, bo, nullptr, nullptr, nullptr, out);
}

// Round 12
// 108.993 us; speedup vs baseline: 1.9297x; 1.1072x over previous
//
#include <hip/hip_runtime.h>
#include <cstdint>
#include <cstddef>
#include <math.h>

// B=2, L=2048, E=1024, H=16, D=64
#define BB 2
#define LL 2048
#define EE 1024
#define HH 16
#define DD 64
#define MM (BB*LL)

typedef short short8 __attribute__((ext_vector_type(8)));
typedef float f32x4 __attribute__((ext_vector_type(4)));
typedef float f32x16 __attribute__((ext_vector_type(16)));

#define GPTR __attribute__((address_space(1)))
#define LPTR __attribute__((address_space(3)))

__device__ __forceinline__ unsigned short f32_bf16(float f) {
  union { float f; unsigned u; } c; c.f = f;
  c.u += 0x7fffu + ((c.u >> 16) & 1u);
  return (unsigned short)(c.u >> 16);
}

__device__ __forceinline__ unsigned pk_bf16(float lo, float hi) {
  unsigned r;
  asm("v_cvt_pk_bf16_f32 %0, %1, %2" : "=v"(r) : "v"(lo), "v"(hi));
  return r;
}
// raw 2^x — no libm range-fixup code. Arg is bounded by defer-max (<= +8),
// and v_exp_f32(-inf) = 0 in hardware, exactly what online softmax needs.
__device__ __forceinline__ float ex2(float x) {
  float r;
  asm("v_exp_f32 %0, %1" : "=v"(r) : "v"(x));
  return r;
}
// v_permlane32_swap_b32 vdst, vsrc — operands must be DISTINCT live values.
__device__ __forceinline__ void swap32(unsigned &a, unsigned &b) {
  asm("v_permlane32_swap_b32 %0, %1" : "+v"(a), "+v"(b));
}
__device__ __forceinline__ float xh_max(float v) {
  union { float f; unsigned u; } a, b;
  a.f = v;
  asm("v_mov_b32 %0, %1" : "=&v"(b.u) : "v"(a.u));
  asm("v_permlane32_swap_b32 %0, %1" : "+v"(a.u), "+v"(b.u));
  return fmaxf(a.f, b.f);
}
__device__ __forceinline__ float xh_sum(float v) {
  union { float f; unsigned u; } a, b;
  a.f = v;
  asm("v_mov_b32 %0, %1" : "=&v"(b.u) : "v"(a.u));
  asm("v_permlane32_swap_b32 %0, %1" : "+v"(a.u), "+v"(b.u));
  return a.f + b.f;
}
__device__ __forceinline__ f32x16 zero16() {
  f32x16 v;
  #pragma unroll
  for (int e = 0; e < 16; ++e) v[e] = 0.f;
  return v;
}

// ---------------- fp32 -> bf16 conversion (x + 4 weights fused) ----------------
__global__ void cvt_all(const float* __restrict__ x,  const float* __restrict__ wq,
                        const float* __restrict__ wk, const float* __restrict__ wv,
                        const float* __restrict__ wo,
                        unsigned short* __restrict__ xb,  unsigned short* __restrict__ wqb,
                        unsigned short* __restrict__ wkb, unsigned short* __restrict__ wvb,
                        unsigned short* __restrict__ wob)
{
  int i = (blockIdx.x * 256 + threadIdx.x) * 4;
  if (i >= MM * EE + 4 * EE * EE) return;
  const float* s; unsigned short* d; int off;
  if (i < MM * EE) { s = x; d = xb; off = i; }
  else {
    int k = i - MM * EE;
    int w = k >> 20;               // EE*EE = 1<<20
    off = k & (EE * EE - 1);
    s = (w == 0) ? wq : (w == 1) ? wk : (w == 2) ? wv : wo;
    d = (w == 0) ? wqb : (w == 1) ? wkb : (w == 2) ? wvb : wob;
  }
  float4 v = *(const float4*)(s + off);
  union { unsigned short s[4]; uint2 u; } o;
  o.s[0] = f32_bf16(v.x); o.s[1] = f32_bf16(v.y);
  o.s[2] = f32_bf16(v.z); o.s[3] = f32_bf16(v.w);
  *(uint2*)(d + off) = o.u;
}

// ---------------- 128x128 bf16 GEMM (NT: A MxK, W NxK) ----------------
template<int MODE>
__global__ __launch_bounds__(256, 2)
void gemm128(const unsigned short* __restrict__ A,
             const unsigned short* __restrict__ W0,
             const unsigned short* __restrict__ W1,
             const unsigned short* __restrict__ W2,
             const float* __restrict__ mask,
             const float* __restrict__ bias,
             unsigned short* __restrict__ O0,
             unsigned short* __restrict__ O1,
             unsigned short* __restrict__ O2,
             float* __restrict__ OF)
{
  constexpr int K = EE;
  const int tid = threadIdx.x;
  const int lane = tid & 63;
  const int wid = tid >> 6;
  const int g = lane >> 4, li = lane & 15;
  const int m0 = blockIdx.y * 128;
  const int n0 = blockIdx.x * 128;
  const int z = blockIdx.z;

  const unsigned short* Wp = W0;
  if (MODE == 0) Wp = (z == 0) ? W0 : ((z == 1) ? W1 : W2);

  __shared__ unsigned short As[128 * 64];
  __shared__ unsigned short Bs[128 * 64];

  f32x4 acc[4][4];
  f32x4 zero = {0.f, 0.f, 0.f, 0.f};
  #pragma unroll
  for (int i = 0; i < 4; ++i)
    #pragma unroll
    for (int j = 0; j < 4; ++j) acc[i][j] = zero;

  const int wm = (wid >> 1) * 64;
  const int wn = (wid & 1) * 64;

  for (int kt = 0; kt < K; kt += 64) {
    #pragma unroll
    for (int j = 0; j < 4; ++j) {
      int c = j * 256 + tid;
      int row = c >> 3;
      int lcol = ((c & 7) * 16) ^ ((row & 7) << 4);
      __builtin_amdgcn_global_load_lds(
        (const GPTR void*)((const char*)(A + (size_t)(m0 + row) * K + kt) + lcol),
        (LPTR void*)((char*)As + c * 16), 16, 0, 0);
      __builtin_amdgcn_global_load_lds(
        (const GPTR void*)((const char*)(Wp + (size_t)(n0 + row) * K + kt) + lcol),
        (LPTR void*)((char*)Bs + c * 16), 16, 0, 0);
    }
    __syncthreads();

    #pragma unroll
    for (int kk = 0; kk < 2; ++kk) {
      short8 a[4], b[4];
      const int colb = (kk * 32 + g * 8) * 2;
      #pragma unroll
      for (int i = 0; i < 4; ++i) {
        int ar = wm + i * 16 + li;
        a[i] = *(const short8*)((const char*)As + ar * 128 + (colb ^ ((ar & 7) << 4)));
        int br = wn + i * 16 + li;
        b[i] = *(const short8*)((const char*)Bs + br * 128 + (colb ^ ((br & 7) << 4)));
      }
      #pragma unroll
      for (int i = 0; i < 4; ++i)
        #pragma unroll
        for (int j = 0; j < 4; ++j)
          acc[i][j] = __builtin_amdgcn_mfma_f32_16x16x32_bf16(a[i], b[j], acc[i][j], 0, 0, 0);
    }
    __syncthreads();
  }

  if (MODE == 0) {
    if (z == 2) {
      // V^T kv-blocked: per head [L/32][D=64][32], each 32-kv tile = 4KB contiguous
      #pragma unroll
      for (int i = 0; i < 4; ++i) {
        int mbase = m0 + wm + i * 16 + g * 4;
        int bb2 = mbase >> 11;
        int l0  = mbase & (LL - 1);
        float mk[4];
        #pragma unroll
        for (int r = 0; r < 4; ++r) mk[r] = mask[mbase + r];
        #pragma unroll
        for (int j = 0; j < 4; ++j) {
          int n = n0 + wn + j * 16 + li;
          int h2 = n >> 6, dd2 = n & 63;
          union { unsigned short s[4]; uint2 u; } o;
          #pragma unroll
          for (int r = 0; r < 4; ++r) o.s[r] = f32_bf16(acc[i][j][r] * mk[r]);
          size_t off = (size_t)(bb2 * HH + h2) * (LL * DD)
                     + (size_t)(l0 >> 5) * (DD * 32) + dd2 * 32 + (l0 & 31);
          *(uint2*)(O2 + off) = o.u;
        }
      }
    } else {
      unsigned short* Op = (z == 0) ? O0 : O1;
      const float sc = (z == 0) ? 0.125f * 1.44269504088896f : 1.0f;
      #pragma unroll
      for (int i = 0; i < 4; ++i) {
        #pragma unroll
        for (int r = 0; r < 4; ++r) {
          int m = m0 + wm + i * 16 + g * 4 + r;
          float mk = mask[m] * sc;
          int bb = m >> 11;
          int l  = m & (LL - 1);
          #pragma unroll
          for (int j = 0; j < 4; ++j) {
            int n = n0 + wn + j * 16 + li;
            int h = n >> 6, d = n & 63;
            size_t off = (((size_t)(bb * HH + h)) * LL + l) * DD + d;
            Op[off] = f32_bf16(acc[i][j][r] * mk);
          }
        }
      }
    }
  } else {
    #pragma unroll
    for (int i = 0; i < 4; ++i) {
      #pragma unroll
      for (int j = 0; j < 4; ++j) {
        int n = n0 + wn + j * 16 + li;
        float bv = bias[n];
        #pragma unroll
        for (int r = 0; r < 4; ++r) {
          int m = m0 + wm + i * 16 + g * 4 + r;
          OF[(size_t)m * EE + n] = acc[i][j][r] + bv;
        }
      }
    }
  }
}

// ---------------- causal flash attention: R9 structure + raw v_exp_f32 ----------
// Block p handles q-tiles qth=63-p AND qtl=p (65 tile-bodies, perfectly balanced).
// One K/V load feeds both q-tiles over the shared kv range.
// 2 waves kv-parity split, private state, single-barrier merge for both tiles.
// Grid: 1024 blocks, XCD-colocated heads.
__global__ __launch_bounds__(128, 2)
void attn8(const unsigned short* __restrict__ Q,
           const unsigned short* __restrict__ K,
           const unsigned short* __restrict__ VT,
           unsigned short* __restrict__ Y)
{
  const int tid = threadIdx.x, lane = tid & 63, w = tid >> 6;
  const int l31 = lane & 31, hi = lane >> 5;

  const int id = blockIdx.x;
  const int lo = id & 7;                    // XCD
  const int r_ = id >> 3;
  const int bh = (r_ & 3) * 8 + lo;         // 4 heads per XCD
  const int p  = r_ >> 2;                   // pair index 0..31
  const int qth = 63 - p;                   // heavy q-tile (32..63)
  const int qtl = p;                        // light q-tile (0..31)
  const int b = bh >> 4, h = bh & (HH - 1);
  const size_t kbase = (size_t)bh * LL * DD;

  const unsigned short* Kg  = K + kbase;
  const unsigned short* VTg = VT + kbase;   // kv-blocked [L/32][64][32]

  const int qrh = qth * 32 + l31;
  const int qrl = qtl * 32 + l31;

  short8 qfh[4], qfl[4];
  {
    const unsigned short* Qr = Q + kbase + (size_t)qrh * DD + hi * 8;
    #pragma unroll
    for (int kc = 0; kc < 4; ++kc) qfh[kc] = *(const short8*)(Qr + kc * 16);
    const unsigned short* Qs = Q + kbase + (size_t)qrl * DD + hi * 8;
    #pragma unroll
    for (int kc = 0; kc < 4; ++kc) qfl[kc] = *(const short8*)(Qs + kc * 16);
  }

  const f32x16 kZero = zero16();            // loop-invariant C-seed for QK^T
  f32x16 oh0 = zero16(), oh1 = zero16(), ol0 = zero16(), ol1 = zero16();
  float mh = -INFINITY, lsh = 0.f, ml = -INFINITY, lsl = 0.f;

  short8 kA[4], vA[4], kB[4], vB[4];

  auto loadtile = [&](short8 (&kk)[4], short8 (&vv)[4], int t2) {
    const int kv0 = t2 << 5;
    const unsigned short* Kp = Kg + ((size_t)(kv0 + l31) << 6) + hi * 8;
    #pragma unroll
    for (int kc = 0; kc < 4; ++kc) kk[kc] = *(const short8*)(Kp + kc * 16);
    const unsigned short* Vp = VTg + (size_t)(kv0 >> 5) * (DD * 32) + l31 * 32 + hi * 8;
    vv[0] = *(const short8*)(Vp);
    vv[1] = *(const short8*)(Vp + 16);
    vv[2] = *(const short8*)(Vp + 32 * 32);
    vv[3] = *(const short8*)(Vp + 32 * 32 + 16);
  };

  loadtile(kA, vA, w);

  // QK^T: S^T seeded from kZero (no per-body zero-init movs)
  auto qk = [&](const short8 (&ck)[4], const short8 (&qf)[4]) -> f32x16 {
    __builtin_amdgcn_s_setprio(1);
    f32x16 s = __builtin_amdgcn_mfma_f32_32x32x16_bf16(ck[0], qf[0], kZero, 0, 0, 0);
    #pragma unroll
    for (int kc = 1; kc < 4; ++kc)
      s = __builtin_amdgcn_mfma_f32_32x32x16_bf16(ck[kc], qf[kc], s, 0, 0, 0);
    __builtin_amdgcn_s_setprio(0);
    return s;
  };

  // online softmax (exp2 domain, raw v_exp) + P frag + PV
  auto process = [&](f32x16 &s, const short8 (&cv)[4],
                     float &mq, float &lq, f32x16 &o0, f32x16 &o1) {
    float r0 = fmaxf(fmaxf(fmaxf(s[0], s[8]),  fmaxf(s[1], s[9])),  fmaxf(s[2], s[10]));
    float r1 = fmaxf(fmaxf(fmaxf(s[3], s[11]), fmaxf(s[4], s[12])), fmaxf(s[5], s[13]));
    float r2 = fmaxf(fmaxf(s[6], s[14]), fmaxf(s[7], s[15]));
    float mv = xh_max(fmaxf(fmaxf(r0, r1), r2));

    if (!__all(mv <= mq + 8.0f)) {           // T13 defer-max (P bounded by 2^8)
      float mnew = fmaxf(mq, mv);
      float al = ex2(mq - mnew);             // mq=-inf -> ex2(-inf)=0, correct
      mq = mnew;
      lq *= al;
      #pragma unroll
      for (int e = 0; e < 16; ++e) { o0[e] *= al; o1[e] *= al; }
    }

    float ra[8];
    #pragma unroll
    for (int e = 0; e < 16; ++e) s[e] = ex2(s[e] - mq);
    #pragma unroll
    for (int e = 0; e < 8; ++e) ra[e] = s[e] + s[e + 8];
    #pragma unroll
    for (int st = 4; st >= 1; st >>= 1)
      #pragma unroll
      for (int e = 0; e < 4; ++e) if (e < st) ra[e] += ra[e + st];
    lq += xh_sum(ra[0]);

    auto mkfrag = [&](int base) -> short8 {
      unsigned a0 = pk_bf16(s[base + 0], s[base + 1]);
      unsigned a1 = pk_bf16(s[base + 2], s[base + 3]);
      unsigned b0 = pk_bf16(s[base + 4], s[base + 5]);
      unsigned b1 = pk_bf16(s[base + 6], s[base + 7]);
      swap32(a0, b0);
      swap32(a1, b1);
      union { unsigned u[4]; short8 s8; } f;
      f.u[0] = a0; f.u[1] = a1; f.u[2] = b0; f.u[3] = b1;
      return f.s8;
    };
    short8 pf0 = mkfrag(0), pf1 = mkfrag(8);

    __builtin_amdgcn_s_setprio(1);
    o0 = __builtin_amdgcn_mfma_f32_32x32x16_bf16(cv[0], pf0, o0, 0, 0, 0);
    o0 = __builtin_amdgcn_mfma_f32_32x32x16_bf16(cv[1], pf1, o0, 0, 0, 0);
    o1 = __builtin_amdgcn_mfma_f32_32x32x16_bf16(cv[2], pf0, o1, 0, 0, 0);
    o1 = __builtin_amdgcn_mfma_f32_32x32x16_bf16(cv[3], pf1, o1, 0, 0, 0);
    __builtin_amdgcn_s_setprio(0);
  };

  auto body = [&](short8 (&ck)[4], short8 (&cv)[4],
                  short8 (&nk)[4], short8 (&nv)[4], int t) {
    if (t + 2 <= qth) loadtile(nk, nv, t + 2);

    {  // heavy q-tile: always active
      f32x16 s = qk(ck, qfh);
      if (t == qth) {
        #pragma unroll
        for (int i = 0; i < 16; ++i) {
          int kvr = (i & 3) + 8 * (i >> 2) + 4 * hi;
          if (kvr > l31) s[i] = -INFINITY;
        }
      }
      process(s, cv, mh, lsh, oh0, oh1);
    }
    if (t <= qtl) {  // light q-tile: shares this tile's K/V
      f32x16 s = qk(ck, qfl);
      if (t == qtl) {
        #pragma unroll
        for (int i = 0; i < 16; ++i) {
          int kvr = (i & 3) + 8 * (i >> 2) + 4 * hi;
          if (kvr > l31) s[i] = -INFINITY;
        }
      }
      process(s, cv, ml, lsl, ol0, ol1);
    }
  };

  for (int t = w; t <= qth; t += 4) {
    body(kA, vA, kB, vB, t);
    if (t + 2 <= qth) body(kB, vB, kA, vA, t + 2);
  }

  // ---- merge the two waves' partials via LDS (single barrier), both q-tiles ----
  __shared__ float mg[2][64][34];
  if (w == 1) {
    mg[0][lane][0] = mh; mg[0][lane][1] = lsh;
    mg[1][lane][0] = ml; mg[1][lane][1] = lsl;
    #pragma unroll
    for (int e = 0; e < 16; ++e) {
      mg[0][lane][2 + e] = oh0[e]; mg[0][lane][18 + e] = oh1[e];
      mg[1][lane][2 + e] = ol0[e]; mg[1][lane][18 + e] = ol1[e];
    }
  }
  __syncthreads();
  if (w == 0) {
    #pragma unroll
    for (int q = 0; q < 2; ++q) {
      float mw = (q == 0) ? mh : ml;
      float lw = (q == 0) ? lsh : lsl;
      const f32x16& o0 = (q == 0) ? oh0 : ol0;
      const f32x16& o1 = (q == 0) ? oh1 : ol1;
      int qrow = (q == 0) ? qrh : qrl;
      float m1 = mg[q][lane][0], l1 = mg[q][lane][1];
      float M = fmaxf(mw, m1);
      float a0 = ex2(fmaxf(mw - M, -200.0f));   // clamp: -inf-(-inf) NaN guard
      float a1 = ex2(fmaxf(m1 - M, -200.0f));
      float Lt = lw * a0 + l1 * a1;
      float inv = 1.0f / Lt;
      unsigned short* Yr = Y + ((size_t)b * LL + qrow) * EE + h * DD;
      #pragma unroll
      for (int rg = 0; rg < 4; ++rg) {
        union { unsigned short s[4]; uint2 u; } u0, u1;
        #pragma unroll
        for (int e = 0; e < 4; ++e) {
          int i = rg * 4 + e;
          u0.s[e] = f32_bf16((o0[i] * a0 + mg[q][lane][2 + i]  * a1) * inv);
          u1.s[e] = f32_bf16((o1[i] * a0 + mg[q][lane][18 + i] * a1) * inv);
        }
        *(uint2*)(Yr + rg * 8 + hi * 4) = u0.u;
        *(uint2*)(Yr + 32 + rg * 8 + hi * 4) = u1.u;
      }
    }
  }
}

// ---------------- launch ----------------
extern "C" void kernel_launch(void* const* d_in, const int* in_sizes, int n_in,
                              void* d_out, int out_size, void* d_ws, size_t ws_size,
                              hipStream_t stream) {
  const float* x    = (const float*)d_in[0];
  const float* mask = (const float*)d_in[1];
  const float* Wq   = (const float*)d_in[2];
  const float* Wk   = (const float*)d_in[3];
  const float* Wv   = (const float*)d_in[4];
  const float* Wo   = (const float*)d_in[5];
  const float* bo   = (const float*)d_in[6];
  float* out = (float*)d_out;

  char* ws = (char*)d_ws;
  unsigned short* xb  = (unsigned short*)(ws);
  unsigned short* wqb = (unsigned short*)(ws + ((size_t)8  << 20));
  unsigned short* wkb = (unsigned short*)(ws + ((size_t)10 << 20));
  unsigned short* wvb = (unsigned short*)(ws + ((size_t)12 << 20));
  unsigned short* wob = (unsigned short*)(ws + ((size_t)14 << 20));
  unsigned short* Qb  = (unsigned short*)(ws + ((size_t)16 << 20));
  unsigned short* Kb  = (unsigned short*)(ws + ((size_t)24 << 20));
  unsigned short* VTb = (unsigned short*)(ws + ((size_t)32 << 20));
  unsigned short* Yb  = (unsigned short*)(ws + ((size_t)40 << 20));

  cvt_all<<<8192, 256, 0, stream>>>(x, Wq, Wk, Wv, Wo, xb, wqb, wkb, wvb, wob);

  gemm128<0><<<dim3(EE / 128, MM / 128, 3), 256, 0, stream>>>(
      xb, wqb, wkb, wvb, mask, nullptr, Qb, Kb, VTb, nullptr);

  attn8<<<dim3(1024), 128, 0, stream>>>(Qb, Kb, VTb, Yb);

  gemm128<1><<<dim3(EE / 128, MM / 128, 1), 256, 0, stream>>>(
      Yb, wob, nullptr, nullptr, nullptr, bo, nullptr, nullptr, nullptr, out);
}